// Round 2
// baseline (513.702 us; speedup 1.0000x reference)
//
#include <hip/hip_runtime.h>

// MultiPrecisionLinear: out[m,o] = sum_i x[m,i] * W[bits[path(m)],o,i] + bias[o]
// M = 262144 (8 paths x 32768 rows), K = 256, N = 256, fp32 in/out.
// Round 4: kill steady-state latency. BM=32 so each wave's full W slice
// (64 cols x 256 K bf16) lives in 128 VGPRs (w[4][8], statically indexed,
// loaded once per block in the SAME burst as the x stage loads). The k-loop
// is pure LDS+MFMA -- zero global loads, zero exposed L2 latency. One
// latency exposure per block, pipelined 16-deep across blocks per SIMD.
// Nontemporal out stores preserve L3 residency of x across dispatches.

typedef float  floatx4  __attribute__((ext_vector_type(4)));
typedef short  shortx8  __attribute__((ext_vector_type(8)));
typedef unsigned short ushortx4 __attribute__((ext_vector_type(4)));

constexpr int DIN  = 256;
constexpr int DOUT = 256;
constexpr int ROWS_PER_PATH = 8 * 4096;   // bpp * S
constexpr int BM   = 32;                  // rows per block (4 waves x full N=256)
constexpr int WBANK_ELEMS = 7 * DOUT * DIN;

__device__ __forceinline__ unsigned short f2bf(float f) {
  // round-to-nearest-even fp32 -> bf16
  union { float f; unsigned u; } c; c.f = f;
  unsigned r = c.u + 0x7fffu + ((c.u >> 16) & 1u);
  return (unsigned short)(r >> 16);
}

__device__ __forceinline__ shortx8 cvt8(floatx4 v0, floatx4 v1) {
  shortx8 h;
  h[0] = (short)f2bf(v0.x); h[1] = (short)f2bf(v0.y);
  h[2] = (short)f2bf(v0.z); h[3] = (short)f2bf(v0.w);
  h[4] = (short)f2bf(v1.x); h[5] = (short)f2bf(v1.y);
  h[6] = (short)f2bf(v1.z); h[7] = (short)f2bf(v1.w);
  return h;
}

// one-time fp32 -> bf16 conversion of the 7-entry weight bank into d_ws
__global__ void convert_w_kernel(const float* __restrict__ w,
                                 unsigned short* __restrict__ o, int n4) {
  int i = blockIdx.x * 256 + threadIdx.x;
  if (i < n4) {
    floatx4 v = ((const floatx4*)w)[i];
    ushortx4 h;
    h.x = f2bf(v.x); h.y = f2bf(v.y); h.z = f2bf(v.z); h.w = f2bf(v.w);
    ((ushortx4*)o)[i] = h;
  }
}

template <bool WBF>
__global__ __launch_bounds__(256, 2)
void mp_linear_kernel(const float* __restrict__ x,
                      const void*  __restrict__ wsel,
                      const float* __restrict__ bias,
                      const int*   __restrict__ bits,
                      float* __restrict__ out) {
  // 32 rows x 256 k of bf16 x, XOR-swizzled (byte ^= (row&7)<<4) so
  // ds_read_b128 frag reads are bank-balanced.
  __shared__ short xs[BM * DIN];          // 16 KiB

  const int tid  = threadIdx.x;
  const int row0 = blockIdx.x * BM;
  const int path = row0 / ROWS_PER_PATH;
  const int widx = bits[path];

  const int lane = tid & 63;
  const int wave = tid >> 6;
  const int n0   = wave * 64;       // wave's N offset (4 waves cover N=256)
  const int quad = lane >> 4;
  const int l16  = lane & 15;

  // ---- burst 1: issue x stage loads (8 float4 / thread, HBM) ----
  const float* xt = x + (size_t)row0 * DIN;
  floatx4 v[8];
#pragma unroll
  for (int c = 0; c < 4; ++c) {
    const float* p = xt + (size_t)(tid + c * 256) * 8;
    v[2 * c]     = *(const floatx4*)p;
    v[2 * c + 1] = *(const floatx4*)(p + 4);
  }

  // ---- burst 2: W preload -- wave's full 64-col x 256-K slice into regs.
  // Statically indexed w[nf][kk] (fully unrolled below) -> stays in VGPRs.
  shortx8 w[4][8];
  if (WBF) {
    const unsigned short* __restrict__ wp =
        (const unsigned short*)wsel + (size_t)widx * (DOUT * DIN)
        + (size_t)(n0 + l16) * DIN + quad * 8;
#pragma unroll
    for (int nf = 0; nf < 4; ++nf)
#pragma unroll
      for (int kk = 0; kk < 8; ++kk)
        w[nf][kk] = *(const shortx8*)(wp + (size_t)(nf * 16) * DIN + kk * 32);
  } else {
    const float* __restrict__ wp =
        (const float*)wsel + (size_t)widx * (DOUT * DIN)
        + (size_t)(n0 + l16) * DIN + quad * 8;
#pragma unroll
    for (int nf = 0; nf < 4; ++nf)
#pragma unroll
      for (int kk = 0; kk < 8; ++kk) {
        const float* p = wp + (size_t)(nf * 16) * DIN + kk * 32;
        w[nf][kk] = cvt8(*(const floatx4*)p, *(const floatx4*)(p + 4));
      }
  }

  // ---- convert + LDS write (waits only on burst 1; burst 2 stays in flight
  // until the pre-barrier drain, by which time it has long arrived) ----
#pragma unroll
  for (int c = 0; c < 4; ++c) {
    const int g   = tid + c * 256;        // float8 chunk index
    const int row = g >> 5;               // 32 chunks per row
    const int col = (g & 31) * 8;         // in shorts
    int byte = (row * DIN + col) * 2;
    byte ^= (row & 7) << 4;
    *(shortx8*)((char*)xs + byte) = cvt8(v[2 * c], v[2 * c + 1]);
  }
  __syncthreads();

  floatx4 acc[2][4];
#pragma unroll
  for (int i = 0; i < 2; ++i)
#pragma unroll
    for (int j = 0; j < 4; ++j)
      acc[i][j] = (floatx4)0.f;

  // ---- k-loop: pure LDS + MFMA, zero global loads ----
#pragma unroll
  for (int kk = 0; kk < 8; ++kk) {
    const int k0 = kk * 32;
    shortx8 xf[2];
#pragma unroll
    for (int mf = 0; mf < 2; ++mf) {
      const int row = mf * 16 + l16;
      int byte = (row * DIN + k0 + quad * 8) * 2;
      byte ^= (row & 7) << 4;
      xf[mf] = *(const shortx8*)((const char*)xs + byte);
    }
#pragma unroll
    for (int mf = 0; mf < 2; ++mf)
#pragma unroll
      for (int nf = 0; nf < 4; ++nf)
        // swapped operands: A=W, B=x -> D[row=o_local, col=m_local]
        acc[mf][nf] = __builtin_amdgcn_mfma_f32_16x16x32_bf16(
            w[nf][kk], xf[mf], acc[mf][nf], 0, 0, 0);
  }

  // epilogue: D layout col = lane&15 (m), row = quad*4 + r (o) -> each lane
  // holds 4 consecutive output cols of one row: float4 nontemporal stores.
  floatx4 bv[4];
#pragma unroll
  for (int nf = 0; nf < 4; ++nf)
    bv[nf] = *(const floatx4*)(bias + n0 + nf * 16 + quad * 4);

#pragma unroll
  for (int mf = 0; mf < 2; ++mf) {
    float* orow = out + (size_t)(row0 + mf * 16 + l16) * DOUT + n0 + quad * 4;
#pragma unroll
    for (int nf = 0; nf < 4; ++nf) {
      floatx4 o4 = acc[mf][nf] + bv[nf];
      __builtin_nontemporal_store(o4, (floatx4*)(orow + nf * 16));
    }
  }
}

extern "C" void kernel_launch(void* const* d_in, const int* in_sizes, int n_in,
                              void* d_out, int out_size, void* d_ws, size_t ws_size,
                              hipStream_t stream) {
  const float* x     = (const float*)d_in[0];
  const float* wbank = (const float*)d_in[1];
  const float* bias  = (const float*)d_in[2];
  const int*   bits  = (const int*)d_in[3];
  float*       out   = (float*)d_out;

  const int total_rows = in_sizes[0] / DIN;   // 262144
  const int grid = total_rows / BM;           // 8192

  const size_t wbf_bytes = (size_t)WBANK_ELEMS * sizeof(unsigned short);  // 917504
  if (ws_size >= wbf_bytes) {
    unsigned short* wbf = (unsigned short*)d_ws;
    const int n4 = WBANK_ELEMS / 4;           // 114688
    convert_w_kernel<<<(n4 + 255) / 256, 256, 0, stream>>>(wbank, wbf, n4);
    mp_linear_kernel<true><<<grid, 256, 0, stream>>>(x, wbf, bias, bits, out);
  } else {
    mp_linear_kernel<false><<<grid, 256, 0, stream>>>(x, wbank, bias, bits, out);
  }
}

// Round 3
// 450.365 us; speedup vs baseline: 1.1406x; 1.1406x over previous
//
#include <hip/hip_runtime.h>

// MultiPrecisionLinear: out[m,o] = sum_i x[m,i] * W[bits[path(m)],o,i] + bias[o]
// M = 262144 (8 paths x 32768 rows), K = 256, N = 256, fp32 in/out.
// Round 5: persistent-block streaming pipeline.
//  - grid = 512 (2 blocks/CU); each block owns 16 tiles (BM=32) of ONE path
//    (path = blockIdx&7 -> one path per XCD; W + x stream stay L2-local).
//  - W slice (64 cols x 256 K bf16) loaded ONCE per block into 128 VGPRs,
//    loop-invariant across the 16-tile runtime loop (statically indexed).
//  - x staged fp32 via global_load_lds into a double-buffered LDS tile;
//    raw s_barrier + counted s_waitcnt vmcnt(8): stage issued first, then
//    compute, then out stores -> the 8 stores stay in flight across the
//    barrier (never drain to 0 in the loop).
//  - bf16 convert on the LDS->reg read path (VALU was 91% idle).
//  - LDS XOR-swizzle byte ^= (row&15)<<4 on BOTH the pre-swizzled global
//    source of global_load_lds and the ds_read addresses (rule #21).

typedef float  floatx4  __attribute__((ext_vector_type(4)));
typedef short  shortx8  __attribute__((ext_vector_type(8)));
typedef unsigned short ushortx4 __attribute__((ext_vector_type(4)));

constexpr int DIN  = 256;
constexpr int DOUT = 256;
constexpr int ROWS_PER_PATH   = 8 * 4096;   // bpp * S = 32768
constexpr int BM              = 32;         // rows per tile
constexpr int BLOCKS_PER_PATH = 64;
constexpr int WBANK_ELEMS     = 7 * DOUT * DIN;

__device__ __forceinline__ unsigned short f2bf(float f) {
  // round-to-nearest-even fp32 -> bf16
  union { float f; unsigned u; } c; c.f = f;
  unsigned r = c.u + 0x7fffu + ((c.u >> 16) & 1u);
  return (unsigned short)(r >> 16);
}

__device__ __forceinline__ shortx8 cvt8(floatx4 v0, floatx4 v1) {
  shortx8 h;
  h[0] = (short)f2bf(v0.x); h[1] = (short)f2bf(v0.y);
  h[2] = (short)f2bf(v0.z); h[3] = (short)f2bf(v0.w);
  h[4] = (short)f2bf(v1.x); h[5] = (short)f2bf(v1.y);
  h[6] = (short)f2bf(v1.z); h[7] = (short)f2bf(v1.w);
  return h;
}

// one-time fp32 -> bf16 conversion of the 7-entry weight bank into d_ws
__global__ void convert_w_kernel(const float* __restrict__ w,
                                 unsigned short* __restrict__ o, int n4) {
  int i = blockIdx.x * 256 + threadIdx.x;
  if (i < n4) {
    floatx4 v = ((const floatx4*)w)[i];
    ushortx4 h;
    h.x = f2bf(v.x); h.y = f2bf(v.y); h.z = f2bf(v.z); h.w = f2bf(v.w);
    ((ushortx4*)o)[i] = h;
  }
}

template <bool WBF>
__global__ __launch_bounds__(256, 2)
void mp_linear_kernel(const float* __restrict__ x,
                      const void*  __restrict__ wsel,
                      const float* __restrict__ bias,
                      const int*   __restrict__ bits,
                      float* __restrict__ out) {
  // double-buffered fp32 x tile: 2 x 32 rows x 256 k = 64 KiB
  __shared__ float xs[2][BM * DIN];

  const int tid  = threadIdx.x;
  const int lane = tid & 63;
  const int wave = tid >> 6;
  const int quad = lane >> 4;
  const int l16  = lane & 15;
  const int n0   = wave * 64;           // wave's N offset (4 waves cover N=256)

  const int path  = blockIdx.x & 7;     // one path per XCD
  const int bslot = blockIdx.x >> 3;    // 0..63 within path
  const int widx  = bits[path];

  // ---- W preload: wave's full 64-col x 256-K slice, loop-invariant regs ----
  shortx8 w[4][8];
  if (WBF) {
    const unsigned short* wp = (const unsigned short*)wsel
        + (size_t)widx * (DOUT * DIN) + (size_t)(n0 + l16) * DIN + quad * 8;
#pragma unroll
    for (int nf = 0; nf < 4; ++nf)
#pragma unroll
      for (int kk = 0; kk < 8; ++kk)
        w[nf][kk] = *(const shortx8*)(wp + (size_t)(nf * 16) * DIN + kk * 32);
  } else {
    const float* wp = (const float*)wsel
        + (size_t)widx * (DOUT * DIN) + (size_t)(n0 + l16) * DIN + quad * 8;
#pragma unroll
    for (int nf = 0; nf < 4; ++nf)
#pragma unroll
      for (int kk = 0; kk < 8; ++kk) {
        const float* p = wp + (size_t)(nf * 16) * DIN + kk * 32;
        w[nf][kk] = cvt8(*(const floatx4*)p, *(const floatx4*)(p + 4));
      }
  }

  floatx4 bv[4];
#pragma unroll
  for (int nf = 0; nf < 4; ++nf)
    bv[nf] = *(const floatx4*)(bias + n0 + nf * 16 + quad * 4);

  const int row_base = path * ROWS_PER_PATH;
  const int TILES    = ROWS_PER_PATH / BM;   // 1024

  // stage one 32x256 fp32 tile: 8 global_load_lds_dwordx4 per thread.
  // LDS dest linear (wave-uniform base + lane*16); global SOURCE pre-swizzled
  // with the same XOR the reader applies.
  auto stage = [&](int buf, int trow0) {
    const char* xb = (const char*)(x + (size_t)trow0 * DIN);
#pragma unroll
    for (int i = 0; i < 8; ++i) {
      const int row = wave * 8 + i;
      const int swz = (row & 15) << 4;
      const char* g = xb + (size_t)row * 1024 + ((lane * 16) ^ swz);
      __builtin_amdgcn_global_load_lds(
          (const __attribute__((address_space(1))) void*)g,
          (__attribute__((address_space(3))) void*)(&xs[buf][row * 256]),
          16, 0, 0);
    }
  };

  int t = bslot;
  stage(0, row_base + t * BM);
  asm volatile("s_waitcnt vmcnt(0)" ::: "memory");
  __builtin_amdgcn_s_barrier();

  int cur = 0;
  for (; t < TILES; t += BLOCKS_PER_PATH) {
    const int tn = t + BLOCKS_PER_PATH;
    const bool has_next = tn < TILES;
    if (has_next) stage(cur ^ 1, row_base + tn * BM);   // issue-early

    floatx4 acc[2][4];
#pragma unroll
    for (int i = 0; i < 2; ++i)
#pragma unroll
      for (int j = 0; j < 4; ++j)
        acc[i][j] = (floatx4)0.f;

    const char* bufc = (const char*)&xs[cur][0];
#pragma unroll
    for (int kk = 0; kk < 8; ++kk) {
      shortx8 xf[2];
#pragma unroll
      for (int mf = 0; mf < 2; ++mf) {
        const int row = mf * 16 + l16;
        const int swz = (row & 15) << 4;
        const int off = row * 1024 + kk * 128 + quad * 32;
        floatx4 f0 = *(const floatx4*)(bufc + (off ^ swz));
        floatx4 f1 = *(const floatx4*)(bufc + ((off + 16) ^ swz));
        xf[mf] = cvt8(f0, f1);
      }
#pragma unroll
      for (int mf = 0; mf < 2; ++mf)
#pragma unroll
        for (int nf = 0; nf < 4; ++nf)
          // swapped operands: A=W, B=x -> D[row=o_local, col=m_local]
          acc[mf][nf] = __builtin_amdgcn_mfma_f32_16x16x32_bf16(
              w[nf][kk], xf[mf], acc[mf][nf], 0, 0, 0);
    }

    // epilogue: D layout col = l16 (m), row = quad*4 + r (o) -> float4 stores
    const int row0t = row_base + t * BM;
#pragma unroll
    for (int mf = 0; mf < 2; ++mf) {
      float* orow = out + (size_t)(row0t + mf * 16 + l16) * DOUT + n0 + quad * 4;
#pragma unroll
      for (int nf = 0; nf < 4; ++nf)
        *(floatx4*)(orow + nf * 16) = acc[mf][nf] + bv[nf];
    }

    if (has_next) {
      // order in flight (oldest first): [<=8 prev stores][8 stage][8 stores]
      // vmcnt(8): stage retired, this tile's stores may remain in flight.
      asm volatile("s_waitcnt vmcnt(8)" ::: "memory");
    }
    __builtin_amdgcn_s_barrier();
    cur ^= 1;
  }
}

extern "C" void kernel_launch(void* const* d_in, const int* in_sizes, int n_in,
                              void* d_out, int out_size, void* d_ws, size_t ws_size,
                              hipStream_t stream) {
  const float* x     = (const float*)d_in[0];
  const float* wbank = (const float*)d_in[1];
  const float* bias  = (const float*)d_in[2];
  const int*   bits  = (const int*)d_in[3];
  float*       out   = (float*)d_out;

  const int total_rows = in_sizes[0] / DIN;            // 262144
  const int P = total_rows / ROWS_PER_PATH;            // 8
  const int grid = P * BLOCKS_PER_PATH;                // 512 = 2 blocks/CU

  const size_t wbf_bytes = (size_t)WBANK_ELEMS * sizeof(unsigned short);
  if (ws_size >= wbf_bytes) {
    unsigned short* wbf = (unsigned short*)d_ws;
    const int n4 = WBANK_ELEMS / 4;
    convert_w_kernel<<<(n4 + 255) / 256, 256, 0, stream>>>(wbank, wbf, n4);
    mp_linear_kernel<true><<<grid, 256, 0, stream>>>(x, wbf, bias, bits, out);
  } else {
    mp_linear_kernel<false><<<grid, 256, 0, stream>>>(x, wbank, bias, bits, out);
  }
}